// Round 12
// baseline (188.414 us; speedup 1.0000x reference)
//
#include <hip/hip_runtime.h>

#define NN 2048
#define HALF 1024
#define CC 128
#define EE 65536
#define CAP 128

typedef unsigned short u16;

__device__ __forceinline__ float sigm(float v){ return 1.0f/(1.0f + __expf(-v)); }

__device__ __forceinline__ float dinv_lo(int i, const int* __restrict__ cnt,
                                         const float* __restrict__ colsum){
  return rsqrtf(1.0f + (float)cnt[i] + colsum[i]);
}
__device__ __forceinline__ float dinv_any(int i, const int* __restrict__ cnt,
                                          const float* __restrict__ colsum){
  float cs = (i < HALF) ? colsum[i] : 0.0f;
  return rsqrtf(1.0f + (float)cnt[i] + cs);
}

// ---------------- K1: prep (640 blocks)
//  all blocks: strided zero of AGG1 + bias-seed of out (plain float4 stores)
//  [0,128):   SpRaw[r][c]=sigm(my[r][c]) (coalesced) + colsum atomics
//  [128,384): bucket sparse edges by dst
//  [384,640): H0 = x @ W1  (8 rows/block, LDS-staged)
__global__ __launch_bounds__(256) void k_prep(
    const float* __restrict__ my, const int* __restrict__ ei, const float* __restrict__ x,
    const float* __restrict__ W1,
    const float* __restrict__ bmu, const float* __restrict__ bls,
    float* __restrict__ SpRaw, float* __restrict__ colsum,
    int* __restrict__ cnt, u16* __restrict__ bucket, float* __restrict__ H0,
    float* __restrict__ AGG1, float* __restrict__ out)
{
  __shared__ float la[8][CC];
  int b = blockIdx.x, t = threadIdx.x;
  int gid = b*256 + t;                    // 0..163839
  if (gid < 65536) {
    ((float4*)AGG1)[gid] = make_float4(0.f,0.f,0.f,0.f);
  } else if (gid < 131072) {
    int i = gid - 65536;                  // float4 index into out (65536 total)
    int g4 = (i & 15)*4;
    const float* bb = (i < 32768) ? bmu : bls;
    ((float4*)out)[i] = make_float4(bb[g4], bb[g4+1], bb[g4+2], bb[g4+3]);
  }

  if (b < 128) {
    int c0 = t*4;
    float cs0=0.f, cs1=0.f, cs2=0.f, cs3=0.f;
    #pragma unroll 2
    for (int rr=0; rr<8; ++rr){
      int r = b*8 + rr;
      float4 v = *(const float4*)(my + (size_t)r*NN + c0);
      float s0=sigm(v.x), s1=sigm(v.y), s2=sigm(v.z), s3=sigm(v.w);
      *(float4*)(SpRaw + (size_t)r*HALF + c0) = make_float4(s0,s1,s2,s3);
      cs0+=s0; cs1+=s1; cs2+=s2; cs3+=s3;
    }
    atomicAdd(&colsum[c0+0], cs0);
    atomicAdd(&colsum[c0+1], cs1);
    atomicAdd(&colsum[c0+2], cs2);
    atomicAdd(&colsum[c0+3], cs3);
  } else if (b < 384) {
    int e = (b-128)*256 + t;
    int s = ei[e], d = ei[EE + e];
    int slot = atomicAdd(&cnt[d], 1);
    if (slot < CAP) bucket[d*CAP + slot] = (u16)s;
  } else {
    int row0 = (b-384)*8;
    #pragma unroll
    for (int i=0;i<4;i++){
      int idx = i*256 + t;
      la[idx>>7][idx&127] = x[(size_t)row0*CC + idx];
    }
    __syncthreads();
    int f = t & 127, rh = t >> 7;
    float o[4] = {0.f,0.f,0.f,0.f};
    #pragma unroll 4
    for (int k=0;k<CC;k++){
      float w = W1[k*CC + f];
      o[0] = fmaf(la[rh*4+0][k], w, o[0]);
      o[1] = fmaf(la[rh*4+1][k], w, o[1]);
      o[2] = fmaf(la[rh*4+2][k], w, o[2]);
      o[3] = fmaf(la[rh*4+3][k], w, o[3]);
    }
    #pragma unroll
    for (int i=0;i<4;i++)
      H0[(size_t)(row0 + rh*4 + i)*CC + f] = o[i];
  }
}

// ---------------- K2: AGG1 = Â H0  (dense K-split x8 w/ LDS-staged dinv + sparse)
//  [0,512):    dense: dbase=(b>>3)*16+half*8, r-chunk (b&7)*128
//  [512,1536): sparse row-pairs
__global__ __launch_bounds__(256) void k_layer1(
  const float* __restrict__ SpRaw, const float* __restrict__ F,
  const int* __restrict__ cnt, const float* __restrict__ colsum,
  const u16* __restrict__ bucket, float* __restrict__ AGG)
{
  __shared__ float ld[128];
  int b = blockIdx.x, t = threadIdx.x;
  if (b < 512) {
    int f = t & 127, half = t >> 7;
    int dbase = (b>>3)*16 + half*8;
    int r0 = (b&7)*128;
    if (t < 128) ld[t] = dinv_lo(r0 + t, cnt, colsum);
    __syncthreads();
    float acc[8];
    #pragma unroll
    for (int j=0;j<8;j++) acc[j] = 0.f;
    #pragma unroll 4
    for (int rr=0; rr<128; ++rr){
      int r = r0 + rr;
      float fv = F[(size_t)r*CC + f] * ld[rr];
      const float4* sp4 = (const float4*)(SpRaw + (size_t)r*HALF + dbase);
      float4 s0 = sp4[0], s1 = sp4[1];
      acc[0] = fmaf(s0.x, fv, acc[0]);
      acc[1] = fmaf(s0.y, fv, acc[1]);
      acc[2] = fmaf(s0.z, fv, acc[2]);
      acc[3] = fmaf(s0.w, fv, acc[3]);
      acc[4] = fmaf(s1.x, fv, acc[4]);
      acc[5] = fmaf(s1.y, fv, acc[5]);
      acc[6] = fmaf(s1.z, fv, acc[6]);
      acc[7] = fmaf(s1.w, fv, acc[7]);
    }
    #pragma unroll
    for (int j=0;j<8;j++)
      atomicAdd(&AGG[(size_t)(dbase+j)*CC + f], acc[j]*dinv_lo(dbase+j, cnt, colsum));
  } else {
    int idx = b - 512;
    int d = idx*2 + (t>>7), f = t & 127;
    float dd = dinv_any(d, cnt, colsum);
    float acc = dd * F[(size_t)d*CC + f];
    int m = cnt[d]; m = m > CAP ? CAP : m;
    const u16* bk = bucket + d*CAP;
    for (int j=0;j<m;j++){
      int s = bk[j];
      acc = fmaf(dinv_any(s, cnt, colsum), F[(size_t)s*CC + f], acc);
    }
    atomicAdd(&AGG[(size_t)d*CC + f], dd*acc);
  }
}

// ---------------- K3: mid (256 blocks): G' = ( relu(AGG1 + b1) @ [Wmu|Wls] ) * dinv[row]
__global__ __launch_bounds__(256) void k_mid(
  const float* __restrict__ AGG1, const float* __restrict__ b1,
  const float* __restrict__ Wmu, const float* __restrict__ Wls,
  const int* __restrict__ cnt, const float* __restrict__ colsum,
  float* __restrict__ G)
{
  __shared__ float la[8][CC];
  int b = blockIdx.x, t = threadIdx.x;
  int row0 = b*8;
  #pragma unroll
  for (int i=0;i<4;i++){
    int idx = i*256 + t;
    float v = AGG1[(size_t)row0*CC + idx] + b1[idx & 127];
    la[idx>>7][idx&127] = v > 0.f ? v : 0.f;
  }
  __syncthreads();
  int f = t & 127, rh = t >> 7;
  int g = f & 63;
  const float* W = (f < 64) ? Wmu : Wls;
  float o[4] = {0.f,0.f,0.f,0.f};
  #pragma unroll 4
  for (int k=0;k<CC;k++){
    float w = W[k*64 + g];
    o[0] = fmaf(la[rh*4+0][k], w, o[0]);
    o[1] = fmaf(la[rh*4+1][k], w, o[1]);
    o[2] = fmaf(la[rh*4+2][k], w, o[2]);
    o[3] = fmaf(la[rh*4+3][k], w, o[3]);
  }
  #pragma unroll
  for (int i=0;i<4;i++){
    int row = row0 + rh*4 + i;
    G[(size_t)row*CC + f] = o[i] * dinv_any(row, cnt, colsum);
  }
}

// ---------------- K4: out += Â-apply on pre-scaled G'  (atomics into bias-seeded d_out)
__global__ __launch_bounds__(256) void k_layer2(
  const float* __restrict__ SpRaw, const float* __restrict__ G,
  const int* __restrict__ cnt, const float* __restrict__ colsum,
  const u16* __restrict__ bucket, float* __restrict__ out)
{
  int b = blockIdx.x, t = threadIdx.x;
  int f = t & 127, g = f & 63;
  size_t obase = (f < 64) ? 0 : (size_t)NN*64;
  if (b < 512) {
    int half = t >> 7;
    int dbase = (b>>3)*16 + half*8;
    int r0 = (b&7)*128;
    float acc[8];
    #pragma unroll
    for (int j=0;j<8;j++) acc[j] = 0.f;
    #pragma unroll 4
    for (int r=r0; r<r0+128; ++r){
      float fv = G[(size_t)r*CC + f];
      const float4* sp4 = (const float4*)(SpRaw + (size_t)r*HALF + dbase);
      float4 s0 = sp4[0], s1 = sp4[1];
      acc[0] = fmaf(s0.x, fv, acc[0]);
      acc[1] = fmaf(s0.y, fv, acc[1]);
      acc[2] = fmaf(s0.z, fv, acc[2]);
      acc[3] = fmaf(s0.w, fv, acc[3]);
      acc[4] = fmaf(s1.x, fv, acc[4]);
      acc[5] = fmaf(s1.y, fv, acc[5]);
      acc[6] = fmaf(s1.z, fv, acc[6]);
      acc[7] = fmaf(s1.w, fv, acc[7]);
    }
    #pragma unroll
    for (int j=0;j<8;j++)
      atomicAdd(&out[obase + (size_t)(dbase+j)*64 + g],
                acc[j]*dinv_lo(dbase+j, cnt, colsum));
  } else {
    int idx = b - 512;
    int d = idx*2 + (t>>7);
    float acc = G[(size_t)d*CC + f];            // self term: dinv[d]*G[d] == G'[d]
    int m = cnt[d]; m = m > CAP ? CAP : m;
    const u16* bk = bucket + d*CAP;
    for (int j=0;j<m;j++){
      int s = bk[j];
      acc += G[(size_t)s*CC + f];               // dinv[s]*G[s] == G'[s]
    }
    atomicAdd(&out[obase + (size_t)d*64 + g], acc * dinv_any(d, cnt, colsum));
  }
}

extern "C" void kernel_launch(void* const* d_in, const int* in_sizes, int n_in,
                              void* d_out, int out_size, void* d_ws, size_t ws_size,
                              hipStream_t stream)
{
  (void)in_sizes; (void)n_in; (void)out_size; (void)ws_size;
  const float* x   = (const float*)d_in[0];
  const float* my  = (const float*)d_in[1];
  const float* W1  = (const float*)d_in[2];
  const float* b1  = (const float*)d_in[3];
  const float* Wmu = (const float*)d_in[4];
  const float* bmu = (const float*)d_in[5];
  const float* Wls = (const float*)d_in[6];
  const float* bls = (const float*)d_in[7];
  const int*   ei  = (const int*)d_in[8];
  float* out = (float*)d_out;
  char* ws = (char*)d_ws;

  // ws layout — memset covers only [0, 12288): cnt, colsum
  int*   cnt    = (int*)  (ws + 0);        //    8192 B (memset 0)
  float* colsum = (float*)(ws + 8192);     //    4096 B (memset 0)
  float* AGG1   = (float*)(ws + 12288);    // 1048576 B (zeroed in k_prep)
  u16*   bucket = (u16*)  (ws + 1060864);  //  524288 B
  float* SpRaw  = (float*)(ws + 1585152);  // 4194304 B
  float* H0     = (float*)(ws + 5779456);  // 1048576 B
  float* G      = (float*)(ws + 6828032);  // 1048576 B

  hipMemsetAsync(ws, 0, 12288, stream);
  k_prep  <<<640,  256, 0, stream>>>(my, ei, x, W1, bmu, bls,
                                     SpRaw, colsum, cnt, bucket, H0, AGG1, out);
  k_layer1<<<1536, 256, 0, stream>>>(SpRaw, H0, cnt, colsum, bucket, AGG1);
  k_mid   <<<256,  256, 0, stream>>>(AGG1, b1, Wmu, Wls, cnt, colsum, G);
  k_layer2<<<1536, 256, 0, stream>>>(SpRaw, G, cnt, colsum, bucket, out);
}

// Round 13
// 172.972 us; speedup vs baseline: 1.0893x; 1.0893x over previous
//
#include <hip/hip_runtime.h>

#define NN 2048
#define HALF 1024
#define CC 128
#define EE 65536
#define CAP 128

typedef unsigned short u16;

__device__ __forceinline__ float sigm(float v){ return 1.0f/(1.0f + __expf(-v)); }

__device__ __forceinline__ float dinv_lo(int i, const int* __restrict__ cnt,
                                         const float* __restrict__ colsum){
  return rsqrtf(1.0f + (float)cnt[i] + colsum[i]);
}
__device__ __forceinline__ float dinv_any(int i, const int* __restrict__ cnt,
                                          const float* __restrict__ colsum){
  float cs = (i < HALF) ? colsum[i] : 0.0f;
  return rsqrtf(1.0f + (float)cnt[i] + cs);
}

// ---------------- K1: prep (640 blocks)
//  all blocks: strided zero of AGG1 + bias-seed of out (plain float4 stores)
//  [0,128):   SpRaw[r][c]=sigm(my[r][c]) (coalesced) + colsum atomics
//  [128,384): bucket sparse edges by dst
//  [384,640): H0 = x @ W1  (8 rows/block, LDS-staged)
__global__ __launch_bounds__(256) void k_prep(
    const float* __restrict__ my, const int* __restrict__ ei, const float* __restrict__ x,
    const float* __restrict__ W1,
    const float* __restrict__ bmu, const float* __restrict__ bls,
    float* __restrict__ SpRaw, float* __restrict__ colsum,
    int* __restrict__ cnt, u16* __restrict__ bucket, float* __restrict__ H0,
    float* __restrict__ AGG1, float* __restrict__ out)
{
  __shared__ float la[8][CC];
  int b = blockIdx.x, t = threadIdx.x;
  int gid = b*256 + t;                    // 0..163839
  if (gid < 65536) {
    ((float4*)AGG1)[gid] = make_float4(0.f,0.f,0.f,0.f);
  } else if (gid < 131072) {
    int i = gid - 65536;                  // float4 index into out (65536 total)
    int g4 = (i & 15)*4;
    const float* bb = (i < 32768) ? bmu : bls;
    ((float4*)out)[i] = make_float4(bb[g4], bb[g4+1], bb[g4+2], bb[g4+3]);
  }

  if (b < 128) {
    int c0 = t*4;
    float cs0=0.f, cs1=0.f, cs2=0.f, cs3=0.f;
    #pragma unroll 2
    for (int rr=0; rr<8; ++rr){
      int r = b*8 + rr;
      float4 v = *(const float4*)(my + (size_t)r*NN + c0);
      float s0=sigm(v.x), s1=sigm(v.y), s2=sigm(v.z), s3=sigm(v.w);
      *(float4*)(SpRaw + (size_t)r*HALF + c0) = make_float4(s0,s1,s2,s3);
      cs0+=s0; cs1+=s1; cs2+=s2; cs3+=s3;
    }
    atomicAdd(&colsum[c0+0], cs0);
    atomicAdd(&colsum[c0+1], cs1);
    atomicAdd(&colsum[c0+2], cs2);
    atomicAdd(&colsum[c0+3], cs3);
  } else if (b < 384) {
    int e = (b-128)*256 + t;
    int s = ei[e], d = ei[EE + e];
    int slot = atomicAdd(&cnt[d], 1);
    if (slot < CAP) bucket[d*CAP + slot] = (u16)s;
  } else {
    int row0 = (b-384)*8;
    #pragma unroll
    for (int i=0;i<4;i++){
      int idx = i*256 + t;
      la[idx>>7][idx&127] = x[(size_t)row0*CC + idx];
    }
    __syncthreads();
    int f = t & 127, rh = t >> 7;
    float o[4] = {0.f,0.f,0.f,0.f};
    #pragma unroll 4
    for (int k=0;k<CC;k++){
      float w = W1[k*CC + f];
      o[0] = fmaf(la[rh*4+0][k], w, o[0]);
      o[1] = fmaf(la[rh*4+1][k], w, o[1]);
      o[2] = fmaf(la[rh*4+2][k], w, o[2]);
      o[3] = fmaf(la[rh*4+3][k], w, o[3]);
    }
    #pragma unroll
    for (int i=0;i<4;i++)
      H0[(size_t)(row0 + rh*4 + i)*CC + f] = o[i];
  }
}

// ---------------- K2: AGG1 = Â H0  (dense K-split x4 w/ LDS-staged dinv + sparse)
__global__ __launch_bounds__(256) void k_layer1(
  const float* __restrict__ SpRaw, const float* __restrict__ F,
  const int* __restrict__ cnt, const float* __restrict__ colsum,
  const u16* __restrict__ bucket, float* __restrict__ AGG)
{
  __shared__ float ld[256];
  int b = blockIdx.x, t = threadIdx.x;
  if (b < 256) {
    int f = t & 127, half = t >> 7;
    int dbase = (b>>2)*16 + half*8;
    int r0 = (b&3)*256;
    ld[t] = dinv_lo(r0 + t, cnt, colsum);
    __syncthreads();
    float acc[8];
    #pragma unroll
    for (int j=0;j<8;j++) acc[j] = 0.f;
    #pragma unroll 4
    for (int rr=0; rr<256; ++rr){
      int r = r0 + rr;
      float fv = F[(size_t)r*CC + f] * ld[rr];
      const float4* sp4 = (const float4*)(SpRaw + (size_t)r*HALF + dbase);
      float4 s0 = sp4[0], s1 = sp4[1];
      acc[0] = fmaf(s0.x, fv, acc[0]);
      acc[1] = fmaf(s0.y, fv, acc[1]);
      acc[2] = fmaf(s0.z, fv, acc[2]);
      acc[3] = fmaf(s0.w, fv, acc[3]);
      acc[4] = fmaf(s1.x, fv, acc[4]);
      acc[5] = fmaf(s1.y, fv, acc[5]);
      acc[6] = fmaf(s1.z, fv, acc[6]);
      acc[7] = fmaf(s1.w, fv, acc[7]);
    }
    #pragma unroll
    for (int j=0;j<8;j++)
      atomicAdd(&AGG[(size_t)(dbase+j)*CC + f], acc[j]*dinv_lo(dbase+j, cnt, colsum));
  } else {
    int idx = b - 256;
    int d = idx*2 + (t>>7), f = t & 127;
    float dd = dinv_any(d, cnt, colsum);
    float acc = dd * F[(size_t)d*CC + f];
    int m = cnt[d]; m = m > CAP ? CAP : m;
    const u16* bk = bucket + d*CAP;
    for (int j=0;j<m;j++){
      int s = bk[j];
      acc = fmaf(dinv_any(s, cnt, colsum), F[(size_t)s*CC + f], acc);
    }
    atomicAdd(&AGG[(size_t)d*CC + f], dd*acc);
  }
}

// ---------------- K3: mid (256 blocks): G' = ( relu(AGG1 + b1) @ [Wmu|Wls] ) * dinv[row]
__global__ __launch_bounds__(256) void k_mid(
  const float* __restrict__ AGG1, const float* __restrict__ b1,
  const float* __restrict__ Wmu, const float* __restrict__ Wls,
  const int* __restrict__ cnt, const float* __restrict__ colsum,
  float* __restrict__ G)
{
  __shared__ float la[8][CC];
  int b = blockIdx.x, t = threadIdx.x;
  int row0 = b*8;
  #pragma unroll
  for (int i=0;i<4;i++){
    int idx = i*256 + t;
    float v = AGG1[(size_t)row0*CC + idx] + b1[idx & 127];
    la[idx>>7][idx&127] = v > 0.f ? v : 0.f;
  }
  __syncthreads();
  int f = t & 127, rh = t >> 7;
  int g = f & 63;
  const float* W = (f < 64) ? Wmu : Wls;
  float o[4] = {0.f,0.f,0.f,0.f};
  #pragma unroll 4
  for (int k=0;k<CC;k++){
    float w = W[k*64 + g];
    o[0] = fmaf(la[rh*4+0][k], w, o[0]);
    o[1] = fmaf(la[rh*4+1][k], w, o[1]);
    o[2] = fmaf(la[rh*4+2][k], w, o[2]);
    o[3] = fmaf(la[rh*4+3][k], w, o[3]);
  }
  #pragma unroll
  for (int i=0;i<4;i++){
    int row = row0 + rh*4 + i;
    G[(size_t)row*CC + f] = o[i] * dinv_any(row, cnt, colsum);
  }
}

// ---------------- K4: out += Â-apply on pre-scaled G'  (atomics into bias-seeded d_out)
__global__ __launch_bounds__(256) void k_layer2(
  const float* __restrict__ SpRaw, const float* __restrict__ G,
  const int* __restrict__ cnt, const float* __restrict__ colsum,
  const u16* __restrict__ bucket, float* __restrict__ out)
{
  int b = blockIdx.x, t = threadIdx.x;
  int f = t & 127, g = f & 63;
  size_t obase = (f < 64) ? 0 : (size_t)NN*64;
  if (b < 256) {
    int half = t >> 7;
    int dbase = (b>>2)*16 + half*8;
    int r0 = (b&3)*256;
    float acc[8];
    #pragma unroll
    for (int j=0;j<8;j++) acc[j] = 0.f;
    #pragma unroll 4
    for (int r=r0; r<r0+256; ++r){
      float fv = G[(size_t)r*CC + f];
      const float4* sp4 = (const float4*)(SpRaw + (size_t)r*HALF + dbase);
      float4 s0 = sp4[0], s1 = sp4[1];
      acc[0] = fmaf(s0.x, fv, acc[0]);
      acc[1] = fmaf(s0.y, fv, acc[1]);
      acc[2] = fmaf(s0.z, fv, acc[2]);
      acc[3] = fmaf(s0.w, fv, acc[3]);
      acc[4] = fmaf(s1.x, fv, acc[4]);
      acc[5] = fmaf(s1.y, fv, acc[5]);
      acc[6] = fmaf(s1.z, fv, acc[6]);
      acc[7] = fmaf(s1.w, fv, acc[7]);
    }
    #pragma unroll
    for (int j=0;j<8;j++)
      atomicAdd(&out[obase + (size_t)(dbase+j)*64 + g],
                acc[j]*dinv_lo(dbase+j, cnt, colsum));
  } else {
    int idx = b - 256;
    int d = idx*2 + (t>>7);
    float acc = G[(size_t)d*CC + f];            // self term: dinv[d]*G[d] == G'[d]
    int m = cnt[d]; m = m > CAP ? CAP : m;
    const u16* bk = bucket + d*CAP;
    for (int j=0;j<m;j++){
      int s = bk[j];
      acc += G[(size_t)s*CC + f];               // dinv[s]*G[s] == G'[s]
    }
    atomicAdd(&out[obase + (size_t)d*64 + g], acc * dinv_any(d, cnt, colsum));
  }
}

extern "C" void kernel_launch(void* const* d_in, const int* in_sizes, int n_in,
                              void* d_out, int out_size, void* d_ws, size_t ws_size,
                              hipStream_t stream)
{
  (void)in_sizes; (void)n_in; (void)out_size; (void)ws_size;
  const float* x   = (const float*)d_in[0];
  const float* my  = (const float*)d_in[1];
  const float* W1  = (const float*)d_in[2];
  const float* b1  = (const float*)d_in[3];
  const float* Wmu = (const float*)d_in[4];
  const float* bmu = (const float*)d_in[5];
  const float* Wls = (const float*)d_in[6];
  const float* bls = (const float*)d_in[7];
  const int*   ei  = (const int*)d_in[8];
  float* out = (float*)d_out;
  char* ws = (char*)d_ws;

  // ws layout — memset covers only [0, 12288): cnt, colsum
  int*   cnt    = (int*)  (ws + 0);        //    8192 B (memset 0)
  float* colsum = (float*)(ws + 8192);     //    4096 B (memset 0)
  float* AGG1   = (float*)(ws + 12288);    // 1048576 B (zeroed in k_prep)
  u16*   bucket = (u16*)  (ws + 1060864);  //  524288 B
  float* SpRaw  = (float*)(ws + 1585152);  // 4194304 B
  float* H0     = (float*)(ws + 5779456);  // 1048576 B
  float* G      = (float*)(ws + 6828032);  // 1048576 B

  hipMemsetAsync(ws, 0, 12288, stream);
  k_prep  <<<640,  256, 0, stream>>>(my, ei, x, W1, bmu, bls,
                                     SpRaw, colsum, cnt, bucket, H0, AGG1, out);
  k_layer1<<<1280, 256, 0, stream>>>(SpRaw, H0, cnt, colsum, bucket, AGG1);
  k_mid   <<<256,  256, 0, stream>>>(AGG1, b1, Wmu, Wls, cnt, colsum, G);
  k_layer2<<<1280, 256, 0, stream>>>(SpRaw, G, cnt, colsum, bucket, out);
}